// Round 8
// baseline (74.908 us; speedup 1.0000x reference)
//
#include <hip/hip_runtime.h>

// FastGaussianModel: values[m] = sum_n exp(-0.5 * sum_d (p[m,d]-q[n,d])^2 * iv[n,d]) * w[n]
//
// Round 8: fan-in restructure on top of R6/R7 (best 74.2us, absmax 3.9e-3).
// Evidence ledger: only inner-loop op-count ever moved time (R6 -3.9us);
// feed-structure x4 and dispatch-count changes all neutral. Last untested
// axis: the write fan-in (16 atomicAdds/point, 800k lane-atomics, per-block
// reduce tail). Change: 4-wave blocks x 8 slice-groups (same 6272 waves,
// ~6.1/SIMD, same sweep), 4-way LDS reduce, atomics/point 16 -> 8, fan-in
// is one thread per point (no loop). Inner loop unchanged: fast path with
// shared log_scales detected at runtime (b.p^2 folded into per-point seed),
// 3 v2f fma + 1 v2f add + 2 exp + 1 v2f acc-fma per gaussian pair.

typedef float v2f __attribute__((ext_vector_type(2)));

constexpr int BLOCK         = 256;                  // 4 waves
constexpr int WAVES_PER_BLK = 4;
constexpr int PTS_PER_LANE  = 4;
constexpr int TILE_PTS      = 64 * PTS_PER_LANE;    // 256 points per block
constexpr int SLICE_GROUPS  = 8;                    // grid.y
constexpr int TOTAL_SLICES  = SLICE_GROUPS * WAVES_PER_BLK;  // 32

// ws layout: [0..15] header (flag, b0, b1, b2, pad...), then pair records.
// record per pair i (16 floats): [a0.xy a1.xy | a2.xy b0.xy | b1.xy b2.xy | c.xy w.xy]

// --- prep: single block; zeroes out, packs records, detects shared scales ---
__global__ void fgm_prep(const float* __restrict__ positions,
                         const float* __restrict__ log_scales,
                         const float* __restrict__ intensities,
                         float* __restrict__ ws,
                         float* __restrict__ out, int out_n,
                         int N, int NpairsPad) {
    __shared__ int smismatch;
    if (threadIdx.x == 0) smismatch = 0;
    __syncthreads();

    // zero the output (harness poisons it; main accumulates with atomics)
    {
        float4 z = make_float4(0.f, 0.f, 0.f, 0.f);
        float4* o4 = (float4*)out;
        int n4 = out_n >> 2;
        for (int i = threadIdx.x; i < n4; i += blockDim.x) o4[i] = z;
        for (int i = (n4 << 2) + threadIdx.x; i < out_n; i += blockDim.x) out[i] = 0.f;
    }

    const float K = -0.7213475204444817f;  // -0.5 * log2(e)
    // reference b (gaussian 0) — broadcast loads
    float r0 = K / (__expf(2.0f*log_scales[0]) + 1e-6f);
    float r1 = K / (__expf(2.0f*log_scales[1]) + 1e-6f);
    float r2 = K / (__expf(2.0f*log_scales[2]) + 1e-6f);

    int mism = 0;
    float* coef = ws + 16;
    for (int i = threadIdx.x; i < NpairsPad; i += blockDim.x) {
        float v[2][8];
        for (int h = 0; h < 2; ++h) {
            int n = 2*i + h;
            float a0=0.f,a1=0.f,a2=0.f,b0=0.f,b1=0.f,b2=0.f,c=0.f,w=0.f;
            if (n < N) {
                float q0 = positions[3*n+0], q1 = positions[3*n+1], q2 = positions[3*n+2];
                b0 = K / (__expf(2.0f*log_scales[3*n+0]) + 1e-6f);
                b1 = K / (__expf(2.0f*log_scales[3*n+1]) + 1e-6f);
                b2 = K / (__expf(2.0f*log_scales[3*n+2]) + 1e-6f);
                a0 = -2.f*b0*q0;  a1 = -2.f*b1*q1;  a2 = -2.f*b2*q2;
                c  = b0*q0*q0 + b1*q1*q1 + b2*q2*q2;
                w  = intensities[n];
                if (b0 != r0 || b1 != r1 || b2 != r2) mism = 1;
            }
            v[h][0]=a0; v[h][1]=a1; v[h][2]=a2; v[h][3]=b0;
            v[h][4]=b1; v[h][5]=b2; v[h][6]=c;  v[h][7]=w;
        }
        float4* o = (float4*)(coef + (size_t)i * 16);
        o[0] = make_float4(v[0][0], v[1][0], v[0][1], v[1][1]);
        o[1] = make_float4(v[0][2], v[1][2], v[0][3], v[1][3]);
        o[2] = make_float4(v[0][4], v[1][4], v[0][5], v[1][5]);
        o[3] = make_float4(v[0][6], v[1][6], v[0][7], v[1][7]);
    }
    if (mism) atomicOr(&smismatch, 1);
    __syncthreads();
    if (threadIdx.x == 0) {
        ws[0] = smismatch ? 1.f : 0.f;
        ws[1] = r0;  ws[2] = r1;  ws[3] = r2;
    }
}

template <bool FAST>
__device__ __forceinline__ void sweep(const v2f* __restrict__ cp, int pairs,
                                      const float* px, const float* py,
                                      const float* pz, const float* pp,
                                      v2f* acc) {
    #pragma unroll 2
    for (int i = 0; i < pairs; ++i) {
        v2f A0 = cp[0], A1 = cp[1], A2 = cp[2];
        v2f B0 = cp[3], B1 = cp[4], B2 = cp[5];
        v2f C  = cp[6], W  = cp[7];
        cp += 8;
        #pragma unroll
        for (int j = 0; j < PTS_PER_LANE; ++j) {
            v2f t;
            if (FAST) {
                t = C + (v2f){pp[j], pp[j]};          // b.p^2 folded per point
            } else {
                t = __builtin_elementwise_fma(B0, (v2f){px[j]*px[j], px[j]*px[j]},  C);
                t = __builtin_elementwise_fma(B1, (v2f){py[j]*py[j], py[j]*py[j]},  t);
                t = __builtin_elementwise_fma(B2, (v2f){pz[j]*pz[j], pz[j]*pz[j]},  t);
            }
            t = __builtin_elementwise_fma(A2, (v2f){pz[j], pz[j]}, t);
            t = __builtin_elementwise_fma(A1, (v2f){py[j], py[j]}, t);
            t = __builtin_elementwise_fma(A0, (v2f){px[j], px[j]}, t);
            v2f g;
            g.x = __builtin_amdgcn_exp2f(t.x);
            g.y = __builtin_amdgcn_exp2f(t.y);
            acc[j] = __builtin_elementwise_fma(g, W, acc[j]);
        }
    }
}

// --- main: 4 waves/block, 4 pts/lane, wave sweeps a 16-pair slice ---
__global__ __launch_bounds__(BLOCK) void fgm_main(const float* __restrict__ points,
                                                  const float* __restrict__ ws,
                                                  float* __restrict__ out,
                                                  int M, int pairsPerSlice) {
    __shared__ float red[WAVES_PER_BLK][TILE_PTS];  // 4 KB

    int lane = threadIdx.x & 63;
    int wave = __builtin_amdgcn_readfirstlane(threadIdx.x >> 6);
    int tileBase = blockIdx.x * TILE_PTS;
    int slice = blockIdx.y * WAVES_PER_BLK + wave;

    // header (uniform)
    bool fast = (ws[0] == 0.f);
    float hb0 = ws[1], hb1 = ws[2], hb2 = ws[3];

    float px[PTS_PER_LANE], py[PTS_PER_LANE], pz[PTS_PER_LANE], pp[PTS_PER_LANE];
    v2f acc[PTS_PER_LANE];
    #pragma unroll
    for (int j = 0; j < PTS_PER_LANE; ++j) {
        int m = tileBase + lane + 64*j;
        float x = 0.f, y = 0.f, z = 0.f;
        if (m < M) { x = points[3*m+0]; y = points[3*m+1]; z = points[3*m+2]; }
        px[j] = x;  py[j] = y;  pz[j] = z;
        pp[j] = hb0*x*x + hb1*y*y + hb2*z*z;   // <= 0
        acc[j] = (v2f){0.f, 0.f};
    }

    const v2f* cp = (const v2f*)(ws + 16) + (size_t)slice * pairsPerSlice * 8;
    if (fast) sweep<true >(cp, pairsPerSlice, px, py, pz, pp, acc);
    else      sweep<false>(cp, pairsPerSlice, px, py, pz, pp, acc);

    #pragma unroll
    for (int j = 0; j < PTS_PER_LANE; ++j)
        red[wave][lane + 64*j] = acc[j].x + acc[j].y;
    __syncthreads();

    // one thread per point: 4-way sum, single atomic (8 per point grid-wide)
    {
        int p = threadIdx.x;            // BLOCK == TILE_PTS
        int m = tileBase + p;
        if (m < M) {
            float s = (red[0][p] + red[1][p]) + (red[2][p] + red[3][p]);
            atomicAdd(&out[m], s);
        }
    }
}

extern "C" void kernel_launch(void* const* d_in, const int* in_sizes, int n_in,
                              void* d_out, int out_size, void* d_ws, size_t ws_size,
                              hipStream_t stream) {
    const float* points      = (const float*)d_in[0];
    const float* positions   = (const float*)d_in[1];
    const float* log_scales  = (const float*)d_in[2];
    const float* intensities = (const float*)d_in[3];
    int M = in_sizes[0] / 3;
    int N = in_sizes[3];

    int Npairs        = (N + 1) / 2;
    int pairsPerSlice = (Npairs + TOTAL_SLICES - 1) / TOTAL_SLICES;   // 16
    int NpairsPad     = pairsPerSlice * TOTAL_SLICES;                 // 512

    float* ws = (float*)d_ws;  // 16-float header + NpairsPad*16 floats

    // prep: zero out + pack coef + detect shared scales (one dispatch)
    fgm_prep<<<1, 256, 0, stream>>>(positions, log_scales, intensities,
                                    ws, (float*)d_out, out_size, N, NpairsPad);

    int tiles = (M + TILE_PTS - 1) / TILE_PTS;   // 196
    dim3 grid(tiles, SLICE_GROUPS);               // 196 x 8, 4 waves/block
    fgm_main<<<grid, BLOCK, 0, stream>>>(points, ws, (float*)d_out,
                                         M, pairsPerSlice);
}

// Round 10
// 74.093 us; speedup vs baseline: 1.0110x; 1.0110x over previous
//
#include <hip/hip_runtime.h>

// FastGaussianModel: values[m] = sum_n exp(-0.5 * sum_d (p[m,d]-q[n,d])^2 * iv[n,d]) * w[n]
//
// Round 10: revert R9's broken identity (folding 2^c' into w underflows while
// 2^(x) overflows for near-center points -> inf*0=NaN; c' MUST stay inside the
// exp argument). Back to R6 math (t = C + pp + a.p <= ~0, safe), with two new
// mechanical levers aimed at the measured latency-stall residual (R3: VALUBusy
// 15% vs issue model -> stalls; R6's 6 waves/SIMD fixed part of it):
//  (a) compile-time trip count: sweep templated on PAIRS=16 -> full unroll,
//      loads hoisted/pipelined across iterations (runtime fallback kept).
//  (b) fast record = 48 B/pair [a0.xy a1.xy | a2.xy c.xy | w.xy pad] ->
//      3 dwordx4 loads/pair instead of 4 (full 64 B record kept for the
//      general-scales fallback path).
// Shape = R6 best: 128 thr (2 waves), 4 pts/lane, 196x16 grid, LDS 2-way
// fan-in + atomics into prep-zeroed out.

typedef float v2f __attribute__((ext_vector_type(2)));

constexpr int BLOCK         = 128;                  // 2 waves
constexpr int WAVES_PER_BLK = 2;
constexpr int PTS_PER_LANE  = 4;
constexpr int TILE_PTS      = 64 * PTS_PER_LANE;    // 256 points per block
constexpr int SLICE_GROUPS  = 16;                   // grid.y
constexpr int TOTAL_SLICES  = SLICE_GROUPS * WAVES_PER_BLK;  // 32
constexpr int HDR           = 16;                   // header floats
constexpr int FASTREC       = 12;                   // floats per fast pair rec (48 B)
constexpr int FULLREC       = 16;                   // floats per full pair rec (64 B)

// ws layout: [0..15] header (flag, b0, b1, b2, ...) |
//   fast table: NpairsPad * 12 floats [a0.xy a1.xy | a2.xy c.xy | w.xy pad2]
//   full table: NpairsPad * 16 floats [a0.xy a1.xy | a2.xy b0.xy |
//                                      b1.xy b2.xy | c.xy  w.xy]

// --- prep: single block; zeroes out, packs both tables, detects shared scales
__global__ void fgm_prep(const float* __restrict__ positions,
                         const float* __restrict__ log_scales,
                         const float* __restrict__ intensities,
                         float* __restrict__ ws,
                         float* __restrict__ out, int out_n,
                         int N, int NpairsPad) {
    __shared__ int smismatch;
    if (threadIdx.x == 0) smismatch = 0;
    __syncthreads();

    // zero the output (harness poisons it; main accumulates with atomics)
    {
        float4 z = make_float4(0.f, 0.f, 0.f, 0.f);
        float4* o4 = (float4*)out;
        int n4 = out_n >> 2;
        for (int i = threadIdx.x; i < n4; i += blockDim.x) o4[i] = z;
        for (int i = (n4 << 2) + threadIdx.x; i < out_n; i += blockDim.x) out[i] = 0.f;
    }

    const float K = -0.7213475204444817f;  // -0.5 * log2(e)
    float r0 = K / (__expf(2.0f*log_scales[0]) + 1e-6f);
    float r1 = K / (__expf(2.0f*log_scales[1]) + 1e-6f);
    float r2 = K / (__expf(2.0f*log_scales[2]) + 1e-6f);

    int mism = 0;
    float* fastT = ws + HDR;
    float* fullT = ws + HDR + (size_t)NpairsPad * FASTREC;
    for (int i = threadIdx.x; i < NpairsPad; i += blockDim.x) {
        float v[2][8];
        for (int h = 0; h < 2; ++h) {
            int n = 2*i + h;
            float a0=0.f,a1=0.f,a2=0.f,b0=0.f,b1=0.f,b2=0.f,c=0.f,w=0.f;
            if (n < N) {
                float q0 = positions[3*n+0], q1 = positions[3*n+1], q2 = positions[3*n+2];
                b0 = K / (__expf(2.0f*log_scales[3*n+0]) + 1e-6f);
                b1 = K / (__expf(2.0f*log_scales[3*n+1]) + 1e-6f);
                b2 = K / (__expf(2.0f*log_scales[3*n+2]) + 1e-6f);
                a0 = -2.f*b0*q0;  a1 = -2.f*b1*q1;  a2 = -2.f*b2*q2;
                c  = b0*q0*q0 + b1*q1*q1 + b2*q2*q2;   // <= 0 (K folded)
                w  = intensities[n];
                if (b0 != r0 || b1 != r1 || b2 != r2) mism = 1;
            }
            v[h][0]=a0; v[h][1]=a1; v[h][2]=a2; v[h][3]=b0;
            v[h][4]=b1; v[h][5]=b2; v[h][6]=c;  v[h][7]=w;
        }
        float4* f = (float4*)(fastT + (size_t)i * FASTREC);
        f[0] = make_float4(v[0][0], v[1][0], v[0][1], v[1][1]);  // a0.xy a1.xy
        f[1] = make_float4(v[0][2], v[1][2], v[0][6], v[1][6]);  // a2.xy c.xy
        f[2] = make_float4(v[0][7], v[1][7], 0.f,     0.f);      // w.xy  pad
        float4* o = (float4*)(fullT + (size_t)i * FULLREC);
        o[0] = make_float4(v[0][0], v[1][0], v[0][1], v[1][1]);
        o[1] = make_float4(v[0][2], v[1][2], v[0][3], v[1][3]);
        o[2] = make_float4(v[0][4], v[1][4], v[0][5], v[1][5]);
        o[3] = make_float4(v[0][6], v[1][6], v[0][7], v[1][7]);
    }
    if (mism) atomicOr(&smismatch, 1);
    __syncthreads();
    if (threadIdx.x == 0) {
        ws[0] = smismatch ? 1.f : 0.f;
        ws[1] = r0;  ws[2] = r1;  ws[3] = r2;
    }
}

// fast sweep: 48 B/pair; PAIRS>0 = compile-time trip count (full unroll)
template <int PAIRS>
__device__ __forceinline__ void sweep_fast(const v2f* __restrict__ cp, int pairs,
                                           const float* px, const float* py,
                                           const float* pz, const float* pp,
                                           v2f* acc) {
    const int n = PAIRS > 0 ? PAIRS : pairs;
    #pragma unroll
    for (int i = 0; i < n; ++i) {
        v2f A0 = cp[0], A1 = cp[1], A2 = cp[2], C = cp[3], W = cp[4];
        cp += 6;
        #pragma unroll
        for (int j = 0; j < PTS_PER_LANE; ++j) {
            v2f t = C + (v2f){pp[j], pp[j]};                    // <= ~0
            t = __builtin_elementwise_fma(A2, (v2f){pz[j], pz[j]}, t);
            t = __builtin_elementwise_fma(A1, (v2f){py[j], py[j]}, t);
            t = __builtin_elementwise_fma(A0, (v2f){px[j], px[j]}, t);
            v2f g;
            g.x = __builtin_amdgcn_exp2f(t.x);
            g.y = __builtin_amdgcn_exp2f(t.y);
            acc[j] = __builtin_elementwise_fma(g, W, acc[j]);
        }
    }
}

// fallback: full 64 B/pair records, general per-gaussian scales
__device__ __forceinline__ void sweep_full(const v2f* __restrict__ cp, int pairs,
                                           const float* px, const float* py,
                                           const float* pz, v2f* acc) {
    #pragma unroll 2
    for (int i = 0; i < pairs; ++i) {
        v2f A0 = cp[0], A1 = cp[1], A2 = cp[2];
        v2f B0 = cp[3], B1 = cp[4], B2 = cp[5];
        v2f C  = cp[6], W  = cp[7];
        cp += 8;
        #pragma unroll
        for (int j = 0; j < PTS_PER_LANE; ++j) {
            v2f t = __builtin_elementwise_fma(B0, (v2f){px[j]*px[j], px[j]*px[j]}, C);
            t = __builtin_elementwise_fma(B1, (v2f){py[j]*py[j], py[j]*py[j]}, t);
            t = __builtin_elementwise_fma(B2, (v2f){pz[j]*pz[j], pz[j]*pz[j]}, t);
            t = __builtin_elementwise_fma(A2, (v2f){pz[j], pz[j]}, t);
            t = __builtin_elementwise_fma(A1, (v2f){py[j], py[j]}, t);
            t = __builtin_elementwise_fma(A0, (v2f){px[j], px[j]}, t);
            v2f g;
            g.x = __builtin_amdgcn_exp2f(t.x);
            g.y = __builtin_amdgcn_exp2f(t.y);
            acc[j] = __builtin_elementwise_fma(g, W, acc[j]);
        }
    }
}

// --- main: 2 waves/block, 4 pts/lane, wave sweeps a PAIRS-pair slice ---
template <int PAIRS>
__global__ __launch_bounds__(BLOCK) void fgm_main(const float* __restrict__ points,
                                                  const float* __restrict__ ws,
                                                  float* __restrict__ out,
                                                  int M, int pairsPerSlice,
                                                  int NpairsPad) {
    __shared__ float red[WAVES_PER_BLK][TILE_PTS];  // 2 KB

    int lane = threadIdx.x & 63;
    int wave = __builtin_amdgcn_readfirstlane(threadIdx.x >> 6);
    int tileBase = blockIdx.x * TILE_PTS;
    int slice = blockIdx.y * WAVES_PER_BLK + wave;

    bool fast = (ws[0] == 0.f);
    float hb0 = ws[1], hb1 = ws[2], hb2 = ws[3];

    float px[PTS_PER_LANE], py[PTS_PER_LANE], pz[PTS_PER_LANE], pp[PTS_PER_LANE];
    v2f acc[PTS_PER_LANE];
    #pragma unroll
    for (int j = 0; j < PTS_PER_LANE; ++j) {
        int m = tileBase + lane + 64*j;
        float x = 0.f, y = 0.f, z = 0.f;
        if (m < M) { x = points[3*m+0]; y = points[3*m+1]; z = points[3*m+2]; }
        px[j] = x;  py[j] = y;  pz[j] = z;
        pp[j] = hb0*x*x + hb1*y*y + hb2*z*z;   // <= 0, per-point seed
        acc[j] = (v2f){0.f, 0.f};
    }

    if (fast) {
        const v2f* cp = (const v2f*)(ws + HDR) + (size_t)slice * pairsPerSlice * 6;
        sweep_fast<PAIRS>(cp, pairsPerSlice, px, py, pz, pp, acc);
    } else {
        const v2f* cp = (const v2f*)(ws + HDR + (size_t)NpairsPad * FASTREC)
                        + (size_t)slice * pairsPerSlice * 8;
        sweep_full(cp, pairsPerSlice, px, py, pz, acc);
    }

    #pragma unroll
    for (int j = 0; j < PTS_PER_LANE; ++j)
        red[wave][lane + 64*j] = acc[j].x + acc[j].y;
    __syncthreads();

    for (int p = threadIdx.x; p < TILE_PTS; p += BLOCK) {
        int m = tileBase + p;
        if (m < M) atomicAdd(&out[m], red[0][p] + red[1][p]);
    }
}

extern "C" void kernel_launch(void* const* d_in, const int* in_sizes, int n_in,
                              void* d_out, int out_size, void* d_ws, size_t ws_size,
                              hipStream_t stream) {
    const float* points      = (const float*)d_in[0];
    const float* positions   = (const float*)d_in[1];
    const float* log_scales  = (const float*)d_in[2];
    const float* intensities = (const float*)d_in[3];
    int M = in_sizes[0] / 3;
    int N = in_sizes[3];

    int Npairs        = (N + 1) / 2;
    int pairsPerSlice = (Npairs + TOTAL_SLICES - 1) / TOTAL_SLICES;   // 16 @ N=1024
    int NpairsPad     = pairsPerSlice * TOTAL_SLICES;                 // 512

    float* ws = (float*)d_ws;

    fgm_prep<<<1, 256, 0, stream>>>(positions, log_scales, intensities,
                                    ws, (float*)d_out, out_size, N, NpairsPad);

    int tiles = (M + TILE_PTS - 1) / TILE_PTS;   // 196
    dim3 grid(tiles, SLICE_GROUPS);               // 196 x 16, 2 waves/block
    if (pairsPerSlice == 16) {
        fgm_main<16><<<grid, BLOCK, 0, stream>>>(points, ws, (float*)d_out,
                                                 M, pairsPerSlice, NpairsPad);
    } else {
        fgm_main<0><<<grid, BLOCK, 0, stream>>>(points, ws, (float*)d_out,
                                                M, pairsPerSlice, NpairsPad);
    }
}